// Round 2
// baseline (244.955 us; speedup 1.0000x reference)
//
#include <hip/hip_runtime.h>
#include <math.h>

#define NN 100000
#define NE 1600000
#define DD 128          // D_IN == D_OUT
#define NB 1563         // 64-node bins: ceil(100000/64)
#define CAP 1280        // per-bin entry capacity; Poisson(1024) max over 1563 bins ~1147
#define PB 391          // partition blocks (4096 edges each, 512 threads)
#define CB 391          // conv blocks (grid-stride, 512 threads)

// ---------------------------------------------------------------------------
// d_ws layout (int32 units), total ~59.2 MB:
//   Hh      [NN*DD fp16]   @ WS_HH   (25.6 MB)
//   cursor  [NB]           @ WS_CUR  (count-only; zeroed via hipMemsetAsync)
//   entries [NB*CAP]       @ WS_ENT  (8.0 MB; packed (src&63)<<17 | dst)
//   Ah      [NN*DD fp16]   @ WS_AH   (25.6 MB)
// ---------------------------------------------------------------------------
#define WS_HH  0
#define WS_CUR 6400000
#define WS_ENT (WS_CUR + NB)
#define WS_AH  (WS_ENT + NB * CAP)

typedef __attribute__((ext_vector_type(8))) _Float16 h8_t;
typedef __attribute__((ext_vector_type(4))) _Float16 h4_t;
typedef __attribute__((ext_vector_type(2))) _Float16 h2_t;
typedef __attribute__((ext_vector_type(4))) float f4_t;

// packed fp32x2 -> fp16x2 (RNE via v_cvt)
__device__ __forceinline__ unsigned pk2h(float x, float y) {
    h2_t h;
    h.x = (_Float16)x;
    h.y = (_Float16)y;
    return *(unsigned*)&h;
}

__device__ __forceinline__ h4_t h4max(h4_t a, h4_t b) {
    return __builtin_elementwise_max(a, b);   // 2x v_pk_max_f16
}

// ---------------------------------------------------------------------------
// Fused prep: blocks [0,PB) partition edges into per-bin regions (LDS count ->
// one global reserve per (block,bin) -> clustered scatter); blocks [PB,PB+CB)
// convert H fp32 -> fp16 (grid-stride). 512-thread blocks: 782 total = 3.06
// blocks/CU (vs 1.53 at 1024 threads -> 2x quantization imbalance).
// ---------------------------------------------------------------------------
__global__ __launch_bounds__(512) void prep_kernel(const float* __restrict__ H,
                                                   const int* __restrict__ src,
                                                   const int* __restrict__ dst,
                                                   int* __restrict__ cursor,
                                                   unsigned* __restrict__ entries,
                                                   uint4* __restrict__ Hh4) {
    __shared__ int cnt[NB];    // 6.25 KB
    __shared__ int gcur[NB];   // 6.25 KB
    const int t = threadIdx.x;
    const int b = blockIdx.x;
    if (b < PB) {
        for (int i = t; i < NB; i += 512) cnt[i] = 0;
        __syncthreads();
        const int base = b * 4096;
        int sv[8];
#pragma unroll
        for (int k = 0; k < 8; ++k) {
            int e = base + k * 512 + t;
            sv[k] = (e < NE) ? src[e] : -1;
            if (sv[k] >= 0) atomicAdd(&cnt[sv[k] >> 6], 1);
        }
        __syncthreads();
        for (int i = t; i < NB; i += 512) {
            int c = cnt[i];
            gcur[i] = c ? i * CAP + atomicAdd(&cursor[i], c) : 0;
        }
        __syncthreads();
#pragma unroll
        for (int k = 0; k < 8; ++k) {
            int e = base + k * 512 + t;
            if (sv[k] >= 0) {
                int s = sv[k];
                int pos = atomicAdd(&gcur[s >> 6], 1);
                entries[pos] = ((unsigned)(s & 63) << 17) | (unsigned)dst[e];
            }
        }
    } else {
        const int nb = b - PB;
        const int n8 = NN * DD / 8;   // 1.6M tasks of 8 elems
        for (int i = nb * 512 + t; i < n8; i += CB * 512) {
            const float4* s = (const float4*)H + (size_t)i * 2;
            float4 a = s[0], c4 = s[1];
            uint4 o;
            o.x = pk2h(a.x, a.y);
            o.y = pk2h(a.z, a.w);
            o.z = pk2h(c4.x, c4.y);
            o.w = pk2h(c4.z, c4.w);
            Hh4[i] = o;
        }
    }
}

// ---------------------------------------------------------------------------
// Atomic-free per-bin segment-max: counting-sort the bin's entries by local
// node (64 counters, wave-0 shfl scan), then each wave processes whole nodes.
// Gather phase: wave splits into two 32-lane halves; each half loads h4 (8B,
// 32 lanes cover the 256B row) over even/odd neighbors, 4 rows in flight per
// half (8 per wave = 2KB) -> half the latency exposures of the old h2 version.
// Halves combined with one shfl_xor(32) per node. fp16 max exact on fp16 data.
// ---------------------------------------------------------------------------
__global__ __launch_bounds__(256) void agg_kernel(const _Float16* __restrict__ Hh,
                                                  const int* __restrict__ cursor,
                                                  const unsigned* __restrict__ entries,
                                                  unsigned* __restrict__ Ah) {
    __shared__ unsigned raw[CAP];
    __shared__ unsigned sorted[CAP];
    __shared__ int cnt[64], base_s[64], cur[64];
    const int t = threadIdx.x;
    const int b = blockIdx.x;
    const int n = cursor[b];

    if (t < 64) cnt[t] = 0;
    __syncthreads();
    for (int i = t; i < n; i += 256) {
        unsigned e = entries[b * CAP + i];
        raw[i] = e;
        atomicAdd(&cnt[e >> 17], 1);
    }
    __syncthreads();
    if (t < 64) {   // threads 0..63 == wave 0
        int v = cnt[t];
        int incl = v;
#pragma unroll
        for (int o = 1; o < 64; o <<= 1) {
            int y = __shfl_up(incl, o, 64);
            if (t >= o) incl += y;
        }
        base_s[t] = incl - v;
        cur[t] = incl - v;
    }
    __syncthreads();
    for (int i = t; i < n; i += 256) {
        unsigned e = raw[i];
        int pos = atomicAdd(&cur[e >> 17], 1);
        sorted[pos] = e & 0x1FFFFu;
    }
    __syncthreads();

    const int lane = t & 63;
    const int w = t >> 6;
    const int half = lane >> 5;        // 0/1: even/odd neighbor indices
    const int l32 = lane & 31;
    const _Float16* __restrict__ colbase = Hh + l32 * 4;   // 8B per lane
#pragma unroll
    for (int q = 0; q < 16; ++q) {
        int ln = w * 16 + q;
        int s0 = base_s[ln];
        int e0 = s0 + cnt[ln];
        unsigned long long mu = 0xFC00FC00FC00FC00ull;   // 4x -inf fp16
        h4_t m = *(h4_t*)&mu;
        int j = s0 + half;
        for (; j + 6 < e0; j += 8) {                     // 4 rows in flight/half
            int d0 = sorted[j], d1 = sorted[j + 2];
            int d2 = sorted[j + 4], d3 = sorted[j + 6];
            h4_t v0 = *(const h4_t*)(colbase + (size_t)d0 * DD);
            h4_t v1 = *(const h4_t*)(colbase + (size_t)d1 * DD);
            h4_t v2 = *(const h4_t*)(colbase + (size_t)d2 * DD);
            h4_t v3 = *(const h4_t*)(colbase + (size_t)d3 * DD);
            m = h4max(m, h4max(h4max(v0, v1), h4max(v2, v3)));
        }
        for (; j < e0; j += 2) {
            h4_t v0 = *(const h4_t*)(colbase + (size_t)sorted[j] * DD);
            m = h4max(m, v0);
        }
        // combine the two halves: each lane gets partner lane^32's partial max
        uint2 mv = *(uint2*)&m;
        uint2 ov;
        ov.x = (unsigned)__shfl_xor((int)mv.x, 32, 64);
        ov.y = (unsigned)__shfl_xor((int)mv.y, 32, 64);
        h4_t om = *(h4_t*)&ov;
        m = h4max(m, om);
        int node = b * 64 + ln;
        if (half == 0 && node < NN) {
            uint2 outv = make_uint2(0u, 0u);
            if (s0 < e0) outv = *(uint2*)&m;
            *(uint2*)(Ah + (size_t)node * 64 + l32 * 2) = outv;
        }
    }
}

// ---------------------------------------------------------------------------
// fp16 MFMA matmul: out[i,o] = b[o] + sum_k X[i,k]*W[o,k], X = [Hh | Ah].
// W converted fp32->fp16 during LDS staging (L2-resident). Block: 64 rows x
// 128 outs, 4 waves, 8 out-tiles of 16x16x32 MFMA, K=256 in 4 chunks of 64.
// Frag layouts (m89/m91, dtype-independent): A[m=lane&15][k=quad*8+j],
// B[k][n=lane&15], C/D row=quad*4+reg, col=lane&15.
// ---------------------------------------------------------------------------
#define XP 72   // LDS row pitch (fp16 elems): 144B -> 2-way bank alias (free)
__global__ __launch_bounds__(256) void mfma_matmul_kernel(
        const unsigned short* __restrict__ Hh,   // [NN][128] fp16
        const unsigned short* __restrict__ Ah,   // [NN][128] fp16
        const float* __restrict__ W,             // [128][256] fp32
        const float* __restrict__ bias,          // [128]
        float* __restrict__ out) {               // [NN][128] fp32
    __shared__ unsigned short Xs[64 * XP];       // 9.2 KB
    __shared__ unsigned short Ws[128 * XP];      // 18.4 KB
    const int t = threadIdx.x;
    const int lane = t & 63;
    const int w = t >> 6;
    const int quad = lane >> 4;
    const int l16 = lane & 15;
    const int blockrow = blockIdx.x * 64;

    f4_t acc[8] = {};

    for (int c = 0; c < 4; ++c) {
        const int k0 = c * 64;
        {
            const unsigned short* xb = (c < 2) ? Hh : Ah;
            const int koff = (c < 2) ? k0 : k0 - 128;
            int seg = t & 7, r0 = t >> 3;        // 8 segs x 8 fp16 = 64 k
#pragma unroll
            for (int j = 0; j < 2; ++j) {
                int r = r0 + 32 * j;
                int row = blockrow + r;
                uint4 v = make_uint4(0, 0, 0, 0);
                if (row < NN)
                    v = *(const uint4*)(xb + (size_t)row * DD + koff + seg * 8);
                *(uint4*)&Xs[r * XP + seg * 8] = v;
            }
        }
        {
            int seg = t & 15, o0 = t >> 4;
#pragma unroll
            for (int j = 0; j < 8; ++j) {
                int o = o0 + 16 * j;
                float4 wv = *(const float4*)(W + (size_t)o * 256 + k0 + seg * 4);
                uint2 p;
                p.x = pk2h(wv.x, wv.y);
                p.y = pk2h(wv.z, wv.w);
                *(uint2*)&Ws[o * XP + seg * 4] = p;
            }
        }
        __syncthreads();
#pragma unroll
        for (int kk = 0; kk < 64; kk += 32) {
            h8_t a = *(const h8_t*)&Xs[(w * 16 + l16) * XP + kk + quad * 8];
#pragma unroll
            for (int ot = 0; ot < 8; ++ot) {
                h8_t bf = *(const h8_t*)&Ws[(ot * 16 + l16) * XP + kk + quad * 8];
                acc[ot] = __builtin_amdgcn_mfma_f32_16x16x32_f16(a, bf, acc[ot], 0, 0, 0);
            }
        }
        __syncthreads();
    }

#pragma unroll
    for (int ot = 0; ot < 8; ++ot) {
        float bv = bias[ot * 16 + l16];
#pragma unroll
        for (int reg = 0; reg < 4; ++reg) {
            int row = blockrow + w * 16 + quad * 4 + reg;
            if (row < NN)
                out[(size_t)row * DD + ot * 16 + l16] = acc[ot][reg] + bv;
        }
    }
}

extern "C" void kernel_launch(void* const* d_in, const int* in_sizes, int n_in,
                              void* d_out, int out_size, void* d_ws, size_t ws_size,
                              hipStream_t stream) {
    const float* H   = (const float*)d_in[0];
    const int*   src = (const int*)d_in[1];
    const int*   dst = (const int*)d_in[2];
    const float* W   = (const float*)d_in[3];
    const float* b   = (const float*)d_in[4];
    float* out = (float*)d_out;

    int* ws = (int*)d_ws;
    unsigned short* Hh      = (unsigned short*)(ws + WS_HH);
    int*            cursor  = ws + WS_CUR;
    unsigned*       entries = (unsigned*)(ws + WS_ENT);
    unsigned*       Ah      = (unsigned*)(ws + WS_AH);

    hipMemsetAsync(cursor, 0, NB * sizeof(int), stream);
    prep_kernel<<<PB + CB, 512, 0, stream>>>(H, src, dst, cursor, entries, (uint4*)Hh);
    agg_kernel<<<NB, 256, 0, stream>>>((const _Float16*)Hh, cursor, entries, Ah);
    mfma_matmul_kernel<<<(NN + 63) / 64, 256, 0, stream>>>(
        Hh, (const unsigned short*)Ah, W, b, out);
}

// Round 3
// 238.299 us; speedup vs baseline: 1.0279x; 1.0279x over previous
//
#include <hip/hip_runtime.h>
#include <math.h>

#define NN 100000
#define NE 1600000
#define DD 128          // D_IN == D_OUT
#define NB 1563         // 64-node bins: ceil(100000/64)
#define CAP 1280        // per-bin entry capacity; Poisson(1024) max over 1563 bins ~1147
#define PB 196          // partition blocks (8192 edges each, 1024 threads)
#define CB 196          // conv blocks (grid-stride)

// ---------------------------------------------------------------------------
// d_ws layout (int32 units), total ~59.3 MB:
//   Hh      [NN*DD fp16]   @ WS_HH   (25.6 MB)
//   cursor  [NB]           @ WS_CUR  (count-only; zeroed by init_kernel)
//   entries [NB*CAP]       @ WS_ENT  (8.0 MB; packed (src&63)<<17 | dst)
//   Ah      [NN*DD fp16]   @ WS_AH   (25.6 MB)
//   Wh      [128*256 fp16] @ WS_WH   (64 KB; W pre-converted once)
// ---------------------------------------------------------------------------
#define WS_HH  0
#define WS_CUR 6400000
#define WS_ENT (WS_CUR + NB)
#define WS_AH  (WS_ENT + NB * CAP)
#define WS_WH  (WS_AH + NN * (DD / 2))

typedef __attribute__((ext_vector_type(8))) _Float16 h8_t;
typedef __attribute__((ext_vector_type(4))) _Float16 h4_t;
typedef __attribute__((ext_vector_type(2))) _Float16 h2_t;
typedef __attribute__((ext_vector_type(4))) float f4_t;

// packed fp32x2 -> fp16x2 (RNE via v_cvt)
__device__ __forceinline__ unsigned pk2h(float x, float y) {
    h2_t h;
    h.x = (_Float16)x;
    h.y = (_Float16)y;
    return *(unsigned*)&h;
}

__device__ __forceinline__ h4_t h4max(h4_t a, h4_t b) {
    return __builtin_elementwise_max(a, b);   // 2x v_pk_max_f16
}

// ---------------------------------------------------------------------------
// init: zero cursor + convert W (fp32 [128][256]) -> Wh (fp16) once.
// Replaces the hipMemsetAsync dispatch and kills 1563x per-block W conversion
// in the matmul kernel.
// ---------------------------------------------------------------------------
__global__ __launch_bounds__(1024) void init_kernel(const float* __restrict__ W,
                                                    unsigned* __restrict__ Wh,
                                                    int* __restrict__ cursor) {
    int i = blockIdx.x * 1024 + threadIdx.x;
    if (i < 128 * 256 / 2) Wh[i] = pk2h(W[2 * i], W[2 * i + 1]);
    int j = i - 128 * 256 / 2;
    if (j >= 0 && j < NB) cursor[j] = 0;
}

// ---------------------------------------------------------------------------
// Fused prep: blocks [0,PB) partition edges into per-bin regions (LDS count ->
// one global reserve per (block,bin) -> clustered scatter); blocks [PB,PB+CB)
// convert H fp32 -> fp16 (grid-stride). 1024-thread geometry (196 blocks):
// proven in round 0; 391-block variant doubled global cursor-atomic traffic.
// ---------------------------------------------------------------------------
__global__ __launch_bounds__(1024) void prep_kernel(const float* __restrict__ H,
                                                    const int* __restrict__ src,
                                                    const int* __restrict__ dst,
                                                    int* __restrict__ cursor,
                                                    unsigned* __restrict__ entries,
                                                    uint4* __restrict__ Hh4) {
    __shared__ int cnt[NB];    // 6.25 KB
    __shared__ int gcur[NB];   // 6.25 KB
    const int t = threadIdx.x;
    const int b = blockIdx.x;
    if (b < PB) {
        for (int i = t; i < NB; i += 1024) cnt[i] = 0;
        __syncthreads();
        const int base = b * 8192;
        int sv[8];
#pragma unroll
        for (int k = 0; k < 8; ++k) {
            int e = base + k * 1024 + t;
            sv[k] = (e < NE) ? src[e] : -1;
            if (sv[k] >= 0) atomicAdd(&cnt[sv[k] >> 6], 1);
        }
        __syncthreads();
        for (int i = t; i < NB; i += 1024) {
            int c = cnt[i];
            gcur[i] = c ? i * CAP + atomicAdd(&cursor[i], c) : 0;
        }
        __syncthreads();
#pragma unroll
        for (int k = 0; k < 8; ++k) {
            int e = base + k * 1024 + t;
            if (sv[k] >= 0) {
                int s = sv[k];
                int pos = atomicAdd(&gcur[s >> 6], 1);
                entries[pos] = ((unsigned)(s & 63) << 17) | (unsigned)dst[e];
            }
        }
    } else {
        const int nb = b - PB;
        const int n8 = NN * DD / 8;   // 1.6M tasks of 8 elems
        for (int i = nb * 1024 + t; i < n8; i += CB * 1024) {
            const float4* s = (const float4*)H + (size_t)i * 2;
            float4 a = s[0], c4 = s[1];
            uint4 o;
            o.x = pk2h(a.x, a.y);
            o.y = pk2h(a.z, a.w);
            o.z = pk2h(c4.x, c4.y);
            o.w = pk2h(c4.z, c4.w);
            Hh4[i] = o;
        }
    }
}

// ---------------------------------------------------------------------------
// Atomic-free per-bin segment-max (counting-sort + gather). Gather is at the
// random-miss floor: FETCH_SIZE == per-XCD compulsory (8 XCD x 25.6MB x 0.86),
// insensitive to per-wave MLP (round-2 A/B). Left unchanged.
// ---------------------------------------------------------------------------
__global__ __launch_bounds__(256) void agg_kernel(const _Float16* __restrict__ Hh,
                                                  const int* __restrict__ cursor,
                                                  const unsigned* __restrict__ entries,
                                                  unsigned* __restrict__ Ah) {
    __shared__ unsigned raw[CAP];
    __shared__ unsigned sorted[CAP];
    __shared__ int cnt[64], base_s[64], cur[64];
    const int t = threadIdx.x;
    const int b = blockIdx.x;
    const int n = cursor[b];

    if (t < 64) cnt[t] = 0;
    __syncthreads();
    for (int i = t; i < n; i += 256) {
        unsigned e = entries[b * CAP + i];
        raw[i] = e;
        atomicAdd(&cnt[e >> 17], 1);
    }
    __syncthreads();
    if (t < 64) {   // threads 0..63 == wave 0
        int v = cnt[t];
        int incl = v;
#pragma unroll
        for (int o = 1; o < 64; o <<= 1) {
            int y = __shfl_up(incl, o, 64);
            if (t >= o) incl += y;
        }
        base_s[t] = incl - v;
        cur[t] = incl - v;
    }
    __syncthreads();
    for (int i = t; i < n; i += 256) {
        unsigned e = raw[i];
        int pos = atomicAdd(&cur[e >> 17], 1);
        sorted[pos] = e & 0x1FFFFu;
    }
    __syncthreads();

    const int lane = t & 63;
    const int w = t >> 6;
    const int half = lane >> 5;        // 0/1: even/odd neighbor indices
    const int l32 = lane & 31;
    const _Float16* __restrict__ colbase = Hh + l32 * 4;   // 8B per lane
#pragma unroll
    for (int q = 0; q < 16; ++q) {
        int ln = w * 16 + q;
        int s0 = base_s[ln];
        int e0 = s0 + cnt[ln];
        unsigned long long mu = 0xFC00FC00FC00FC00ull;   // 4x -inf fp16
        h4_t m = *(h4_t*)&mu;
        int j = s0 + half;
        for (; j + 6 < e0; j += 8) {                     // 4 rows in flight/half
            int d0 = sorted[j], d1 = sorted[j + 2];
            int d2 = sorted[j + 4], d3 = sorted[j + 6];
            h4_t v0 = *(const h4_t*)(colbase + (size_t)d0 * DD);
            h4_t v1 = *(const h4_t*)(colbase + (size_t)d1 * DD);
            h4_t v2 = *(const h4_t*)(colbase + (size_t)d2 * DD);
            h4_t v3 = *(const h4_t*)(colbase + (size_t)d3 * DD);
            m = h4max(m, h4max(h4max(v0, v1), h4max(v2, v3)));
        }
        for (; j < e0; j += 2) {
            h4_t v0 = *(const h4_t*)(colbase + (size_t)sorted[j] * DD);
            m = h4max(m, v0);
        }
        // combine the two halves: each lane gets partner lane^32's partial max
        uint2 mv = *(uint2*)&m;
        uint2 ov;
        ov.x = (unsigned)__shfl_xor((int)mv.x, 32, 64);
        ov.y = (unsigned)__shfl_xor((int)mv.y, 32, 64);
        h4_t om = *(h4_t*)&ov;
        m = h4max(m, om);
        int node = b * 64 + ln;
        if (half == 0 && node < NN) {
            uint2 outv = make_uint2(0u, 0u);
            if (s0 < e0) outv = *(uint2*)&m;
            *(uint2*)(Ah + (size_t)node * 64 + l32 * 2) = outv;
        }
    }
}

// ---------------------------------------------------------------------------
// fp16 MFMA matmul v2: 128 rows x 128 outs per block (grid 782), 4 waves.
// W staged from pre-converted Wh via raw uint4 (no fp32 loads, no pk2h).
// Each wave: 32 rows (2 m-subtiles) x 8 n-tiles = 16 acc tiles, K=256 in
// 4 chunks of 64. Frag layouts (m89/m91): A[m=lane&15][k=quad*8+j],
// B[k][n=lane&15], C/D row=quad*4+reg, col=lane&15.
// ---------------------------------------------------------------------------
#define XP 72   // LDS row pitch (fp16 elems): 144B -> 2-way bank alias (free)
__global__ __launch_bounds__(256) void mfma_matmul_kernel(
        const unsigned short* __restrict__ Hh,   // [NN][128] fp16
        const unsigned short* __restrict__ Ah,   // [NN][128] fp16
        const unsigned short* __restrict__ Wh,   // [128][256] fp16
        const float* __restrict__ bias,          // [128]
        float* __restrict__ out) {               // [NN][128] fp32
    __shared__ unsigned short Xs[128 * XP];      // 18.4 KB
    __shared__ unsigned short Ws[128 * XP];      // 18.4 KB
    const int t = threadIdx.x;
    const int lane = t & 63;
    const int w = t >> 6;
    const int quad = lane >> 4;
    const int l16 = lane & 15;
    const int blockrow = blockIdx.x * 128;

    f4_t acc[2][8] = {};

    for (int c = 0; c < 4; ++c) {
        const int k0 = c * 64;
        {
            const unsigned short* xb = (c < 2) ? Hh : Ah;
            const int koff = (c < 2) ? k0 : k0 - 128;
            const int seg = t & 7, r0 = t >> 3;   // 8 segs x 8 fp16 = 64 k
#pragma unroll
            for (int j = 0; j < 4; ++j) {
                int r = r0 + 32 * j;
                int row = blockrow + r;
                uint4 v = make_uint4(0, 0, 0, 0);
                if (row < NN)
                    v = *(const uint4*)(xb + (size_t)row * DD + koff + seg * 8);
                *(uint4*)&Xs[r * XP + seg * 8] = v;
            }
        }
        {
            const int seg = t & 7, o0 = t >> 3;
#pragma unroll
            for (int j = 0; j < 4; ++j) {
                int o = o0 + 32 * j;
                uint4 v = *(const uint4*)(Wh + (size_t)o * 256 + k0 + seg * 8);
                *(uint4*)&Ws[o * XP + seg * 8] = v;
            }
        }
        __syncthreads();
#pragma unroll
        for (int kk = 0; kk < 64; kk += 32) {
            h8_t a0 = *(const h8_t*)&Xs[(w * 32 + l16) * XP + kk + quad * 8];
            h8_t a1 = *(const h8_t*)&Xs[(w * 32 + 16 + l16) * XP + kk + quad * 8];
#pragma unroll
            for (int ot = 0; ot < 8; ++ot) {
                h8_t bf = *(const h8_t*)&Ws[(ot * 16 + l16) * XP + kk + quad * 8];
                acc[0][ot] = __builtin_amdgcn_mfma_f32_16x16x32_f16(a0, bf, acc[0][ot], 0, 0, 0);
                acc[1][ot] = __builtin_amdgcn_mfma_f32_16x16x32_f16(a1, bf, acc[1][ot], 0, 0, 0);
            }
        }
        __syncthreads();
    }

#pragma unroll
    for (int ot = 0; ot < 8; ++ot) {
        float bv = bias[ot * 16 + l16];
#pragma unroll
        for (int sub = 0; sub < 2; ++sub) {
#pragma unroll
            for (int reg = 0; reg < 4; ++reg) {
                int row = blockrow + w * 32 + sub * 16 + quad * 4 + reg;
                if (row < NN)
                    out[(size_t)row * DD + ot * 16 + l16] = acc[sub][ot][reg] + bv;
            }
        }
    }
}

extern "C" void kernel_launch(void* const* d_in, const int* in_sizes, int n_in,
                              void* d_out, int out_size, void* d_ws, size_t ws_size,
                              hipStream_t stream) {
    const float* H   = (const float*)d_in[0];
    const int*   src = (const int*)d_in[1];
    const int*   dst = (const int*)d_in[2];
    const float* W   = (const float*)d_in[3];
    const float* b   = (const float*)d_in[4];
    float* out = (float*)d_out;

    int* ws = (int*)d_ws;
    unsigned short* Hh      = (unsigned short*)(ws + WS_HH);
    int*            cursor  = ws + WS_CUR;
    unsigned*       entries = (unsigned*)(ws + WS_ENT);
    unsigned*       Ah      = (unsigned*)(ws + WS_AH);
    unsigned*       Wh      = (unsigned*)(ws + WS_WH);

    init_kernel<<<18, 1024, 0, stream>>>(W, Wh, cursor);
    prep_kernel<<<PB + CB, 1024, 0, stream>>>(H, src, dst, cursor, entries, (uint4*)Hh);
    agg_kernel<<<NB, 256, 0, stream>>>((const _Float16*)Hh, cursor, entries, Ah);
    mfma_matmul_kernel<<<(NN + 127) / 128, 256, 0, stream>>>(
        Hh, (const unsigned short*)Ah, (const unsigned short*)Wh, b, out);
}